// Round 10
// baseline (430.708 us; speedup 1.0000x reference)
//
#include <hip/hip_runtime.h>
#include <hip/hip_bf16.h>
#include <math.h>

typedef __attribute__((ext_vector_type(8))) short short8;
typedef __attribute__((ext_vector_type(4))) float f32x4;

#define MU_  0.1f
#define THR_ 0.01f
#define ZB_  272   // zero blocks: pad rows 0,57 of YA+YB = 69,632 short8 / 256

static __device__ inline short f2bf(float f) {
    __hip_bfloat16 h = __float2bfloat16(f);
    return *reinterpret_cast<short*>(&h);
}
static __device__ inline float bf2f(unsigned short u) {
    unsigned int x = ((unsigned int)u) << 16;
    return __builtin_bit_cast(float, x);
}

// ---------------------------------------------------------------------------
// Merged prep: [0,ZB_) zero pad ROWS (0,57) of YA+YB; [ZB_,ZB_+32) wnorm;
// rest pack_x. (Rp no longer exists — R lives in LDS inside conv_fused.)
//  Wf2[t][ci>>3][co][ci&7] = Wn[co][ci*9+t]        (fwd A, k-major chunks)
//  Wt2[t][co>>3][ci][co&7] = Wn[co][ci*9+(8-t)]    (conv_t A, k-major chunks)
// ---------------------------------------------------------------------------
__global__ __launch_bounds__(256) void prep_kernel(
    const float* __restrict__ x, const float* __restrict__ W,
    short* __restrict__ YA, short* __restrict__ YB,
    short* __restrict__ Xp, short* __restrict__ Wf2, short* __restrict__ Wt2) {
    __shared__ float lx[64 * 57];
    const int bid = blockIdx.x, tid = threadIdx.x;
    if (bid < ZB_) {
        int gid = bid * 256 + tid;          // [0, 69632)
        const short8 z = {0, 0, 0, 0, 0, 0, 0, 0};
        short* Yb = (gid < 34816) ? YA : YB;
        int g2 = (gid < 34816) ? gid : gid - 34816;
        int ridx = g2 / 1088, off = g2 - ridx * 1088;   // 32 rows x 1088 short8
        int n = ridx >> 1, row = (ridx & 1) * 57;
        ((short8*)(Yb + ((size_t)(n * 58 + row) * 68) * 128))[off] = z;
    } else if (bid < ZB_ + 32) {
        int co = (bid - ZB_) * 4 + (tid >> 6);
        int ci = tid & 63;
        const float* wp = W + (co * 64 + ci) * 9;
        float v[9]; float s = 0.f;
#pragma unroll
        for (int t = 0; t < 9; ++t) { v[t] = wp[t]; s += v[t] * v[t]; }
#pragma unroll
        for (int off = 32; off; off >>= 1) s += __shfl_xor(s, off, 64);
        float inv = 1.0f / sqrtf(s + 1e-12f);
#pragma unroll
        for (int t = 0; t < 9; ++t) {
            Wf2[((t * 8 + (ci >> 3)) * 128 + co) * 8 + (ci & 7)] = f2bf(v[t] * inv);
            Wt2[((t * 16 + (co >> 3)) * 64 + ci) * 8 + (co & 7)] = f2bf(v[8 - t] * inv);
        }
    } else {
        int pb = bid - ZB_ - 32;
        int row = pb % 58, n = pb / 58;
        short* dst = Xp + ((size_t)(n * 58 + row) * 68) * 64;
        if (row >= 1 && row <= 56) {
            int h = row - 1;
            for (int j = tid; j < 64 * 56; j += 256) {
                int ci = j / 56, w = j - ci * 56;
                lx[ci * 57 + w] = x[((size_t)(n * 64 + ci)) * 3136 + h * 56 + w];
            }
            __syncthreads();
            for (int j = tid; j < 68 * 64; j += 256) {
                int s = j >> 6, ci = j & 63;
                float val = (s >= 2 && s < 58) ? lx[ci * 57 + (s - 2)] : 0.f;
                dst[(s << 6) + (ci ^ ((s & 7) << 3))] = f2bf(val);
            }
        } else {
            for (int j = tid; j < 68 * 64; j += 256) dst[j] = 0;
        }
    }
}

// LDS pad-slot zeroing for a 4-row window: slots {0,1,58..67}, shorts 0..63.
static __device__ __forceinline__ void zero_lds_pads4(short* smem, int tid) {
    const short8 z = {0, 0, 0, 0, 0, 0, 0, 0};
    for (int i = tid; i < 384; i += 256) {
        int sr = i >> 3, w = i & 7;
        int row = sr / 12, sl = sr - row * 12;
        int s = (sl < 2) ? sl : sl + 56;
        *(short8*)(smem + (row * 68 + s) * 72 + w * 8) = z;
    }
}

// ---------------------------------------------------------------------------
// Forward conv 64->128, row-PAIR blocks (R9-verified, mode 0 use only here):
// it0 from Xp. grid = 448: sid0 = (bid&7)*112 + (bid>>3)*2.
// ---------------------------------------------------------------------------
__global__ __launch_bounds__(256, 2) void conv_fwd(
    const short* __restrict__ inp,   // [n][58][68][64] bf16 swz (Xp)
    const short* __restrict__ Wf2,   // [9][8][128][8] bf16 k-major chunks
    short* __restrict__ Yp,          // [n][58][68][128] bf16 swz (y state)
    short* __restrict__ Cp) {        // [n][58][68][128] bf16 swz (c_prev)
    __shared__ __align__(16) short smem[19584];   // staging; tables alias it
    const int bid = blockIdx.x, tid = threadIdx.x;
    const int sid0 = (bid & 7) * 112 + (bid >> 3) * 2;
    const int n = sid0 / 56, r0 = sid0 - n * 56 + 1;
    zero_lds_pads4(smem, tid);
    {   // stage 4 input rows r0-1..r0+2, interior slots (1792 short8 items)
        const short8* src = (const short8*)(inp + ((size_t)(n * 58 + (r0 - 1)) * 68) * 64);
        for (int j = tid; j < 1792; j += 256) {
            int sr = j >> 3, w = j & 7;
            int row = sr / 56, s = sr - row * 56 + 2;
            *(short8*)(smem + (row * 68 + s) * 72 + w * 8) = src[(row * 68 + s) * 8 + w];
        }
    }
    const int lane = tid & 63, ct = tid >> 6, quad = lane >> 4, l15 = lane & 15;
    const int cog = ct & 1, pxg = ct >> 1;
    size_t prow[2];
    prow[0] = ((size_t)(n * 58 + r0) * 68) * 128;
    prow[1] = prow[0] + 68 * 128;
    __syncthreads();

    f32x4 acc[2][2][4];
#pragma unroll
    for (int rw = 0; rw < 2; ++rw)
#pragma unroll
        for (int pt = 0; pt < 2; ++pt)
#pragma unroll
            for (int cot = 0; cot < 4; ++cot) acc[rw][pt][cot] = (f32x4){0.f, 0.f, 0.f, 0.f};

#pragma unroll
    for (int f = 0; f < 18; ++f) {            // 18 k-frags; A shared by rows
        const int t = f >> 1, half = f & 1;
        const int dh = t / 3, dw = t % 3;
        const int u = l15 + dw + 1;
        const int phys = (half * 4 + quad) ^ (u & 7);
        short8 areg[4];
#pragma unroll
        for (int cot = 0; cot < 4; ++cot) {
            const int co = cog * 64 + cot * 16 + l15;
            areg[cot] = *(const short8*)(Wf2 +
                ((size_t)((t * 8 + half * 4 + quad) * 128 + co)) * 8);
        }
#pragma unroll
        for (int rw = 0; rw < 2; ++rw) {
#pragma unroll
            for (int pt = 0; pt < 2; ++pt) {
                const int pti = pxg * 2 + pt;
                const short8 bv = *(const short8*)(smem +
                    ((dh + rw) * 68 + pti * 16 + u) * 72 + phys * 8);
#pragma unroll
                for (int cot = 0; cot < 4; ++cot)
                    acc[rw][pt][cot] = __builtin_amdgcn_mfma_f32_16x16x32_bf16(areg[cot], bv, acc[rw][pt][cot], 0, 0, 0);
            }
        }
    }

    // ---- epilogue mode0: y = cp = shrink(MU*acc); tables ALIAS staging ----
    __syncthreads();                 // staging dead (alias safe)
    short* tbase = smem;             // [rw][y|c][64 px][72 ch-half]
#pragma unroll
    for (int hh = 0; hh < 2; ++hh) {
        if (cog == hh) {
#pragma unroll
            for (int rw = 0; rw < 2; ++rw) {
                short* tb_y = tbase + rw * 9216;
                short* tb_c = tb_y + 4608;
#pragma unroll
                for (int pt = 0; pt < 2; ++pt) {
                    const int px = pxg * 32 + pt * 16 + l15;
#pragma unroll
                    for (int cot = 0; cot < 4; ++cot) {
#pragma unroll
                        for (int reg = 0; reg < 4; ++reg) {
                            const int lch = cot * 16 + quad * 4 + reg;
                            const int slot = px * 72 + (lch ^ ((px & 3) << 3));
                            float c = fmaxf(MU_ * acc[rw][pt][cot][reg] - THR_, 0.f);
                            short cb16 = f2bf(c);
                            tb_y[slot] = cb16;
                            tb_c[slot] = cb16;
                        }
                    }
                }
            }
        }
        __syncthreads();
        for (int item = tid; item < 448; item += 256) {
            int vv = item >> 3, g = item & 7;
            int so = vv * 72 + 8 * (g ^ (vv & 3));
            int s = vv + 2;
            int xo = 8 * ((g + 8 * hh) ^ (s & 7));
#pragma unroll
            for (int rw = 0; rw < 2; ++rw) {
                short* tb_y = tbase + rw * 9216;
                short8 yv = *(const short8*)(tb_y + so);
                short8 cv = *(const short8*)(tb_y + 4608 + so);
                size_t off = prow[rw] + (size_t)s * 128 + xo;
                *(short8*)(Yp + off) = yv;
                *(short8*)(Cp + off) = cv;
            }
        }
        if (hh == 0) __syncthreads();
    }
}

// ---------------------------------------------------------------------------
// Fused FISTA iteration, row-QUAD blocks. grid = 224:
// sid0 = (bid&7)*112 + (bid>>3)*4 (XCD-local; quads never straddle images).
// Phase A (conv_t): 8-row Y window (2 chunk-half passes) -> R rows r0-1..r0+4
// computed as 3 row-pairs -> LDS R-tile (pad rows forced zero, identical to
// the old Rp pads). Phase B (conv_fwd): 2 row-pair passes reading B from the
// R-tile (R5-verified math). Reads Ycur, writes Ynext: no cross-block races.
// LDS: win[8][68][72]=76.5KB | Rt[6][68][72]=57.4KB = 134 KB -> 1 block/CU.
// mode 1: state update; mode 2 (last): fp32 out only.
// ---------------------------------------------------------------------------
__global__ __launch_bounds__(256, 1) void conv_fused(
    const short* __restrict__ Ycur,  // [n][58][68][128] bf16 swz (old y)
    const short* __restrict__ Wt2,   // [9][16][64][8]
    const short* __restrict__ Wf2,   // [9][8][128][8]
    const short* __restrict__ Xp,    // [n][58][68][64]
    short* __restrict__ Ynext,       // new y (mode 1)
    short* __restrict__ Cp,          // c_prev, RW rows r0..r0+3 (mode 1)
    float* __restrict__ outp, int mode, float beta) {
    __shared__ __align__(16) short smem[68544];   // win 39168 | Rt 29376
    short* win = smem;
    short* Rt  = smem + 39168;
    const int bid = blockIdx.x, tid = threadIdx.x;
    const int sid0 = (bid & 7) * 112 + (bid >> 3) * 4;
    const int n = sid0 / 56, r0 = sid0 - n * 56 + 1;
    const int lane = tid & 63, ct = tid >> 6, quad = lane >> 4, l15 = lane & 15;
    const short8 z8 = {0, 0, 0, 0, 0, 0, 0, 0};

    // zero pads: win 8 rows x 12 slots; Rt 6 rows x 12 slots
    for (int i = tid; i < 768; i += 256) {
        int sr = i >> 3, w = i & 7;
        int wr = sr / 12, sl = sr - wr * 12;
        int s = (sl < 2) ? sl : sl + 56;
        *(short8*)(win + (wr * 68 + s) * 72 + w * 8) = z8;
    }
    for (int i = tid; i < 576; i += 256) {
        int sr = i >> 3, w = i & 7;
        int rr = sr / 12, sl = sr - rr * 12;
        int s = (sl < 2) ? sl : sl + 56;
        *(short8*)(Rt + (rr * 68 + s) * 72 + w * 8) = z8;
    }

    // shared item->slot mapping for x/y prefetch & table bounce (448 items)
    int pvv[2], pg[2]; bool pok[2];
#pragma unroll
    for (int k = 0; k < 2; ++k) {
        int item = tid + k * 256;
        pok[k] = item < 448;
        pvv[k] = item >> 3; pg[k] = item & 7;
    }

    // ===================== phase A: conv_t rows r0-1..r0+4 ==================
    f32x4 acc3[3][2][4];
#pragma unroll
    for (int p3 = 0; p3 < 3; ++p3)
#pragma unroll
        for (int rw = 0; rw < 2; ++rw)
#pragma unroll
            for (int cit = 0; cit < 4; ++cit) acc3[p3][rw][cit] = (f32x4){0.f, 0.f, 0.f, 0.f};

    short8 xold[3][2][2];
#pragma unroll
    for (int p = 0; p < 2; ++p) {
        if (p) __syncthreads();       // half-0 B reads complete
        // stage window half p: 8 rows (r0-2..r0+5, out-of-range -> zero)
        for (int j = tid; j < 3584; j += 256) {
            int sr = j >> 3, w = j & 7;
            int wr = sr / 56, s = sr - wr * 56 + 2;
            int gr = r0 - 2 + wr;
            short8 v = z8;
            if (gr >= 0 && gr <= 57)
                v = *(const short8*)(Ycur +
                    ((size_t)(n * 58 + gr) * 68 + s) * 128 + p * 64 + w * 8);
            *(short8*)(win + (wr * 68 + s) * 72 + w * 8) = v;
        }
        __syncthreads();
        if (p == 1) {   // x prefetch; latency hides under half-1 compute
#pragma unroll
            for (int p3 = 0; p3 < 3; ++p3)
#pragma unroll
                for (int rw = 0; rw < 2; ++rw) {
                    int gr = r0 - 1 + 2 * p3 + rw;
                    size_t xrow = ((size_t)(n * 58 + gr) * 68) * 64;
#pragma unroll
                    for (int k = 0; k < 2; ++k) if (pok[k]) {
                        int s = pvv[k] + 2;
                        xold[p3][rw][k] = *(const short8*)(Xp + xrow +
                            (size_t)s * 64 + 8 * (pg[k] ^ (s & 7)));
                    }
                }
        }
#pragma unroll
        for (int f = 0; f < 18; ++f) {
            const int t = f >> 1, sh = f & 1;
            const int dh = t / 3, dw = t % 3;
            const int u = l15 + dw + 1;
            const int phys = (sh * 4 + quad) ^ (u & 7);
            short8 areg[4];
#pragma unroll
            for (int cit = 0; cit < 4; ++cit)
                areg[cit] = *(const short8*)(Wt2 +
                    ((size_t)((t * 16 + (p * 2 + sh) * 4 + quad) * 64 + cit * 16 + l15)) * 8);
#pragma unroll
            for (int p3 = 0; p3 < 3; ++p3)
#pragma unroll
                for (int rw = 0; rw < 2; ++rw) {
                    const short8 bv = *(const short8*)(win +
                        ((2 * p3 + rw + dh) * 68 + ct * 16 + u) * 72 + phys * 8);
#pragma unroll
                    for (int cit = 0; cit < 4; ++cit)
                        acc3[p3][rw][cit] = __builtin_amdgcn_mfma_f32_16x16x32_bf16(areg[cit], bv, acc3[p3][rw][cit], 0, 0, 0);
                }
        }
    }

    // ---- conv_t epilogue: r = x - acc -> R-tile (tables alias win) ----
    __syncthreads();                  // window dead
    short* tb = smem;                 // [2 rw][64 px][72]
#pragma unroll
    for (int p3 = 0; p3 < 3; ++p3) {
#pragma unroll
        for (int rw = 0; rw < 2; ++rw)
#pragma unroll
            for (int k = 0; k < 2; ++k) if (pok[k])
                *(short8*)(tb + rw * 4608 + pvv[k] * 72 + 8 * (pg[k] ^ (pvv[k] & 3))) = xold[p3][rw][k];
        __syncthreads();
        {
            const int px = ct * 16 + l15;
#pragma unroll
            for (int rw = 0; rw < 2; ++rw) {
                short* tbr = tb + rw * 4608;
#pragma unroll
                for (int cit = 0; cit < 4; ++cit)
#pragma unroll
                    for (int reg = 0; reg < 4; ++reg) {
                        const int cir = cit * 16 + quad * 4 + reg;
                        const int slot = px * 72 + (cir ^ ((px & 3) << 3));
                        float xv = bf2f((unsigned short)tbr[slot]);
                        tbr[slot] = f2bf(xv - acc3[p3][rw][cit][reg]);
                    }
            }
        }
        __syncthreads();
        for (int item = tid; item < 448; item += 256) {
            int vv = item >> 3, g = item & 7;
            int so = vv * 72 + 8 * (g ^ (vv & 3));
            int s = vv + 2;
#pragma unroll
            for (int rw = 0; rw < 2; ++rw) {
                int gr = r0 - 1 + 2 * p3 + rw;
                short8 val = (gr >= 1 && gr <= 56)
                    ? *(const short8*)(tb + rw * 4608 + so) : z8;
                *(short8*)(Rt + ((2 * p3 + rw) * 68 + s) * 72 + 8 * (g ^ (s & 7))) = val;
            }
        }
        __syncthreads();              // tables reusable
    }

    // ===================== phase B: conv_fwd rows r0..r0+3 ==================
    const int cog = ct & 1, pxg = ct >> 1;
#pragma unroll
    for (int fp = 0; fp < 2; ++fp) {
        const int q0 = r0 + 2 * fp;
        size_t prow[2];
        prow[0] = ((size_t)(n * 58 + q0) * 68) * 128;
        prow[1] = prow[0] + 68 * 128;

        // prefetch half-0 old y / c_prev for both rows of this pair
        short8 yold8[2][2], cold8[2][2];
#pragma unroll
        for (int k = 0; k < 2; ++k) if (pok[k]) {
            int s = pvv[k] + 2;
            int xo = 8 * (pg[k] ^ (s & 7));
#pragma unroll
            for (int rw = 0; rw < 2; ++rw) {
                size_t off = prow[rw] + (size_t)s * 128 + xo;
                yold8[rw][k] = *(const short8*)(Ycur + off);
                if (mode == 1) cold8[rw][k] = *(const short8*)(Cp + off);
            }
        }

        f32x4 acc[2][2][4];
#pragma unroll
        for (int rw = 0; rw < 2; ++rw)
#pragma unroll
            for (int pt = 0; pt < 2; ++pt)
#pragma unroll
                for (int cot = 0; cot < 4; ++cot) acc[rw][pt][cot] = (f32x4){0.f, 0.f, 0.f, 0.f};

#pragma unroll
        for (int f = 0; f < 18; ++f) {
            const int t = f >> 1, half = f & 1;
            const int dh = t / 3, dw = t % 3;
            const int u = l15 + dw + 1;
            const int phys = (half * 4 + quad) ^ (u & 7);
            short8 areg[4];
#pragma unroll
            for (int cot = 0; cot < 4; ++cot) {
                const int co = cog * 64 + cot * 16 + l15;
                areg[cot] = *(const short8*)(Wf2 +
                    ((size_t)((t * 8 + half * 4 + quad) * 128 + co)) * 8);
            }
#pragma unroll
            for (int rw = 0; rw < 2; ++rw) {
#pragma unroll
                for (int pt = 0; pt < 2; ++pt) {
                    const int pti = pxg * 2 + pt;
                    const short8 bv = *(const short8*)(Rt +
                        ((2 * fp + rw + dh) * 68 + pti * 16 + u) * 72 + phys * 8);
#pragma unroll
                    for (int cot = 0; cot < 4; ++cot)
                        acc[rw][pt][cot] = __builtin_amdgcn_mfma_f32_16x16x32_bf16(areg[cot], bv, acc[rw][pt][cot], 0, 0, 0);
                }
            }
        }

        // ---- fwd epilogue (R5-verified), tables alias win (disjoint Rt) ----
        __syncthreads();
        short* tbase = smem;          // [rw][y|c][64 px][72 ch-half]
        const int h0 = q0 - 1;
#pragma unroll
        for (int hh = 0; hh < 2; ++hh) {
#pragma unroll
            for (int rw = 0; rw < 2; ++rw) {
                short* tb_y = tbase + rw * 9216;
                short* tb_c = tb_y + 4608;
#pragma unroll
                for (int k = 0; k < 2; ++k) if (pok[k]) {
                    int o = pvv[k] * 72 + 8 * (pg[k] ^ (pvv[k] & 3));
                    *(short8*)(tb_y + o) = yold8[rw][k];
                    if (mode == 1) *(short8*)(tb_c + o) = cold8[rw][k];
                }
            }
            __syncthreads();
            if (hh == 0) {            // half-1 loads early
#pragma unroll
                for (int k = 0; k < 2; ++k) if (pok[k]) {
                    int s = pvv[k] + 2;
                    int xo = 8 * ((pg[k] + 8) ^ (s & 7));
#pragma unroll
                    for (int rw = 0; rw < 2; ++rw) {
                        size_t off = prow[rw] + (size_t)s * 128 + xo;
                        yold8[rw][k] = *(const short8*)(Ycur + off);
                        if (mode == 1) cold8[rw][k] = *(const short8*)(Cp + off);
                    }
                }
            }
            if (cog == hh) {
#pragma unroll
                for (int rw = 0; rw < 2; ++rw) {
                    short* tb_y = tbase + rw * 9216;
                    short* tb_c = tb_y + 4608;
#pragma unroll
                    for (int pt = 0; pt < 2; ++pt) {
                        const int px = pxg * 32 + pt * 16 + l15;
#pragma unroll
                        for (int cot = 0; cot < 4; ++cot) {
#pragma unroll
                            for (int reg = 0; reg < 4; ++reg) {
                                const int lch = cot * 16 + quad * 4 + reg;
                                const int slot = px * 72 + (lch ^ ((px & 3) << 3));
                                const float a = acc[rw][pt][cot][reg];
                                if (mode == 1) {
                                    float yold = bf2f((unsigned short)tb_y[slot]);
                                    float cold = bf2f((unsigned short)tb_c[slot]);
                                    float c = fmaxf(yold + MU_ * a - THR_, 0.f);
                                    tb_y[slot] = f2bf(c + beta * (c - cold));
                                    tb_c[slot] = f2bf(c);
                                } else {
                                    if (px < 56) {
                                        float yold = bf2f((unsigned short)tb_y[slot]);
                                        float c = fmaxf(yold + MU_ * a - THR_, 0.f);
                                        outp[((size_t)(n * 128 + hh * 64 + lch)) * 3136 + (h0 + rw) * 56 + px] = c;
                                    }
                                }
                            }
                        }
                    }
                }
            }
            if (mode == 1) {
                __syncthreads();
                for (int item = tid; item < 448; item += 256) {
                    int vv = item >> 3, g = item & 7;
                    int so = vv * 72 + 8 * (g ^ (vv & 3));
                    int s = vv + 2;
                    int xo = 8 * ((g + 8 * hh) ^ (s & 7));
#pragma unroll
                    for (int rw = 0; rw < 2; ++rw) {
                        short* tb_y = tbase + rw * 9216;
                        short8 yv = *(const short8*)(tb_y + so);
                        short8 cv = *(const short8*)(tb_y + 4608 + so);
                        size_t off = prow[rw] + (size_t)s * 128 + xo;
                        *(short8*)(Ynext + off) = yv;
                        *(short8*)(Cp + off) = cv;
                    }
                }
            }
            __syncthreads();          // tables free (next hh / next fp)
        }
    }
}

// ---------------------------------------------------------------------------
extern "C" void kernel_launch(void* const* d_in, const int* in_sizes, int n_in,
                              void* d_out, int out_size, void* d_ws, size_t ws_size,
                              hipStream_t stream) {
    const float* x = (const float*)d_in[0];   // [16,64,56,56] fp32
    const float* W = (const float*)d_in[1];   // [128,64,3,3]  fp32
    float* out = (float*)d_out;               // [16,128,56,56] fp32

    // ws layout (all bf16): Xp | YA | YB | Cp | Wf2 | Wt2  (~57 MB)
    const size_t XPN = (size_t)16 * 58 * 68 * 64;   // 4,038,656
    const size_t YPN = 2 * XPN;                      // 8,077,312
    short* Xp = (short*)d_ws;
    short* YA = Xp + XPN;
    short* YB = YA + YPN;
    short* Cp = YB + YPN;
    short* Wf2 = Cp + YPN;                // 73728 shorts
    short* Wt2 = Wf2 + 73728;             // 73728 shorts

    const int prep_blocks = ZB_ + 32 + 58 * 16;     // 1232
    hipLaunchKernelGGL(prep_kernel, dim3(prep_blocks), dim3(256), 0, stream,
                       x, W, YA, YB, Xp, Wf2, Wt2);

    dim3 b(256, 1, 1);
    // it0: c = shrink(MU * conv(x)); y = cp = c  -> YA, Cp
    hipLaunchKernelGGL(conv_fwd, dim3(448), b, 0, stream, Xp, Wf2, YA, Cp);
    double t = 1.0;
    for (int it = 1; it <= 5; ++it) {
        double tn = (1.0 + sqrt(1.0 + 4.0 * t * t)) / 2.0;
        float beta = (float)((t - 1.0) / tn);
        short* Ycur  = (it & 1) ? YA : YB;
        short* Ynext = (it & 1) ? YB : YA;
        hipLaunchKernelGGL(conv_fused, dim3(224), b, 0, stream,
                           Ycur, Wt2, Wf2, Xp, Ynext, Cp,
                           (it == 5) ? out : (float*)nullptr,
                           (it == 5) ? 2 : 1, beta);
        t = tn;
    }
}

// Round 12
// 344.286 us; speedup vs baseline: 1.2510x; 1.2510x over previous
//
#include <hip/hip_runtime.h>
#include <hip/hip_bf16.h>
#include <math.h>

typedef __attribute__((ext_vector_type(8))) short short8;
typedef __attribute__((ext_vector_type(4))) float f32x4;

#define MU_  0.1f
#define THR_ 0.01f
#define ZB_  204   // zero blocks: pad rows 0,57 of Rp+Yp = 52,224 short8 / 256

static __device__ inline short f2bf(float f) {
    __hip_bfloat16 h = __float2bfloat16(f);
    return *reinterpret_cast<short*>(&h);
}
static __device__ inline float bf2f(unsigned short u) {
    unsigned int x = ((unsigned int)u) << 16;
    return __builtin_bit_cast(float, x);
}

// ---------------------------------------------------------------------------
// Merged prep: [0,ZB_) zero pad ROWS (0,57) of Rp+Yp only; [ZB_,ZB_+32) wnorm;
// rest pack_x. (Pad columns never read from global — staging is interior-only
// and conv kernels LDS-memset pad slots.)
//  Wf2[t][ci>>3][co][ci&7] = Wn[co][ci*9+t]        (fwd A, k-major chunks)
//  Wt2[t][co>>3][ci][co&7] = Wn[co][ci*9+(8-t)]    (conv_t A, k-major chunks)
// ---------------------------------------------------------------------------
__global__ __launch_bounds__(256) void prep_kernel(
    const float* __restrict__ x, const float* __restrict__ W,
    short* __restrict__ Rp, short* __restrict__ Yp,
    short* __restrict__ Xp, short* __restrict__ Wf2, short* __restrict__ Wt2) {
    __shared__ float lx[64 * 57];
    const int bid = blockIdx.x, tid = threadIdx.x;
    if (bid < ZB_) {
        int gid = bid * 256 + tid;          // [0, 52224)
        const short8 z = {0, 0, 0, 0, 0, 0, 0, 0};
        if (gid < 17408) {                  // Rp pad rows: 32 rows x 544 short8
            int ridx = gid / 544, off = gid - ridx * 544;
            int n = ridx >> 1, row = (ridx & 1) * 57;
            ((short8*)(Rp + ((size_t)(n * 58 + row) * 68) * 64))[off] = z;
        } else {                            // Yp pad rows: 32 rows x 1088 short8
            int g2 = gid - 17408;
            int ridx = g2 / 1088, off = g2 - ridx * 1088;
            int n = ridx >> 1, row = (ridx & 1) * 57;
            ((short8*)(Yp + ((size_t)(n * 58 + row) * 68) * 128))[off] = z;
        }
    } else if (bid < ZB_ + 32) {
        int co = (bid - ZB_) * 4 + (tid >> 6);
        int ci = tid & 63;
        const float* wp = W + (co * 64 + ci) * 9;
        float v[9]; float s = 0.f;
#pragma unroll
        for (int t = 0; t < 9; ++t) { v[t] = wp[t]; s += v[t] * v[t]; }
#pragma unroll
        for (int off = 32; off; off >>= 1) s += __shfl_xor(s, off, 64);
        float inv = 1.0f / sqrtf(s + 1e-12f);
#pragma unroll
        for (int t = 0; t < 9; ++t) {
            Wf2[((t * 8 + (ci >> 3)) * 128 + co) * 8 + (ci & 7)] = f2bf(v[t] * inv);
            Wt2[((t * 16 + (co >> 3)) * 64 + ci) * 8 + (co & 7)] = f2bf(v[8 - t] * inv);
        }
    } else {
        int pb = bid - ZB_ - 32;
        int row = pb % 58, n = pb / 58;
        short* dst = Xp + ((size_t)(n * 58 + row) * 68) * 64;
        if (row >= 1 && row <= 56) {
            int h = row - 1;
            for (int j = tid; j < 64 * 56; j += 256) {
                int ci = j / 56, w = j - ci * 56;
                lx[ci * 57 + w] = x[((size_t)(n * 64 + ci)) * 3136 + h * 56 + w];
            }
            __syncthreads();
            for (int j = tid; j < 68 * 64; j += 256) {
                int s = j >> 6, ci = j & 63;
                float val = (s >= 2 && s < 58) ? lx[ci * 57 + (s - 2)] : 0.f;
                dst[(s << 6) + (ci ^ ((s & 7) << 3))] = f2bf(val);
            }
        } else {
            for (int j = tid; j < 68 * 64; j += 256) dst[j] = 0;
        }
    }
}

// LDS pad-slot zeroing for a 4-row window: slots {0,1,58..67}, shorts 0..63.
// 4 rows x 12 slots x 8 short8 = 384 items. Disjoint from staged slots [2,58).
static __device__ __forceinline__ void zero_lds_pads4(short* smem, int tid) {
    const short8 z = {0, 0, 0, 0, 0, 0, 0, 0};
    for (int i = tid; i < 384; i += 256) {
        int sr = i >> 3, w = i & 7;
        int row = sr / 12, sl = sr - row * 12;
        int s = (sl < 2) ? sl : sl + 56;
        *(short8*)(smem + (row * 68 + s) * 72 + w * 8) = z;
    }
}

// ---------------------------------------------------------------------------
// Forward conv 64->128, row-PAIR blocks: each block computes rows r0,r0+1
// (all 128 co) from a shared 4-row staged window. grid = 448:
// sid0 = (bid&7)*112 + (bid>>3)*2 (XCD-local, pairs never straddle images).
// Waves 2x2: cog = ct&1 (64 co), pxg = ct>>1 (32 px); acc[2 rows][2 pt][4 cot].
// LDS: 4x68x72 staging (19584 sh) + 4 tables (18432 sh) = 76 KB, 2 blocks/CU.
// mode 0: c=shrink(MU*acc); y=cp=c
// mode 1: c=shrink(y_old+MU*acc); y=c+beta*(c-cp_old); cp=c
// mode 2: out=shrink(y_old+MU*acc) (fp32 NCHW, no state writes)
// ---------------------------------------------------------------------------
__global__ __launch_bounds__(256, 2) void conv_fwd(
    const short* __restrict__ inp,   // [n][58][68][64] bf16 swz (Xp or Rp)
    const short* __restrict__ Wf2,   // [9][8][128][8] bf16 k-major chunks
    short* __restrict__ Yp,          // [n][58][68][128] bf16 swz (y state)
    short* __restrict__ Cp,          // [n][58][68][128] bf16 swz (c_prev)
    float* __restrict__ outp, int mode, float beta) {
    __shared__ __align__(16) short smem[38016];
    const int bid = blockIdx.x, tid = threadIdx.x;
    const int sid0 = (bid & 7) * 112 + (bid >> 3) * 2;
    const int n = sid0 / 56, r0 = sid0 - n * 56 + 1;
    zero_lds_pads4(smem, tid);
    {   // stage 4 input rows r0-1..r0+2, interior slots (1792 short8 items)
        const short8* src = (const short8*)(inp + ((size_t)(n * 58 + (r0 - 1)) * 68) * 64);
        for (int j = tid; j < 1792; j += 256) {
            int sr = j >> 3, w = j & 7;
            int row = sr / 56, s = sr - row * 56 + 2;
            *(short8*)(smem + (row * 68 + s) * 72 + w * 8) = src[(row * 68 + s) * 8 + w];
        }
    }
    const int lane = tid & 63, ct = tid >> 6, quad = lane >> 4, l15 = lane & 15;
    const int cog = ct & 1, pxg = ct >> 1;
    size_t prow[2];
    prow[0] = ((size_t)(n * 58 + r0) * 68) * 128;
    prow[1] = prow[0] + 68 * 128;

    // pre-loop coalesced prefetch of half-0 old y / c_prev for BOTH rows
    short8 yold8[2][2], cold8[2][2];
    int pvv[2], pg[2]; bool pok[2];
#pragma unroll
    for (int k = 0; k < 2; ++k) {
        int item = tid + k * 256;
        pok[k] = item < 448;
        pvv[k] = item >> 3; pg[k] = item & 7;
        if (mode != 0 && pok[k]) {
            int s = pvv[k] + 2;
            int xo = 8 * (pg[k] ^ (s & 7));
#pragma unroll
            for (int rw = 0; rw < 2; ++rw) {
                size_t off = prow[rw] + (size_t)s * 128 + xo;
                yold8[rw][k] = *(const short8*)(Yp + off);
                if (mode == 1) cold8[rw][k] = *(const short8*)(Cp + off);
            }
        }
    }
    __syncthreads();

    f32x4 acc[2][2][4];
#pragma unroll
    for (int rw = 0; rw < 2; ++rw)
#pragma unroll
        for (int pt = 0; pt < 2; ++pt)
#pragma unroll
            for (int cot = 0; cot < 4; ++cot) acc[rw][pt][cot] = (f32x4){0.f, 0.f, 0.f, 0.f};

#pragma unroll
    for (int f = 0; f < 18; ++f) {            // 18 k-frags; A shared by rows
        const int t = f >> 1, half = f & 1;
        const int dh = t / 3, dw = t % 3;
        const int u = l15 + dw + 1;
        const int phys = (half * 4 + quad) ^ (u & 7);
        short8 areg[4];
#pragma unroll
        for (int cot = 0; cot < 4; ++cot) {
            const int co = cog * 64 + cot * 16 + l15;
            areg[cot] = *(const short8*)(Wf2 +
                ((size_t)((t * 8 + half * 4 + quad) * 128 + co)) * 8);
        }
#pragma unroll
        for (int rw = 0; rw < 2; ++rw) {
#pragma unroll
            for (int pt = 0; pt < 2; ++pt) {
                const int pti = pxg * 2 + pt;
                const short8 bv = *(const short8*)(smem +
                    ((dh + rw) * 68 + pti * 16 + u) * 72 + phys * 8);
#pragma unroll
                for (int cot = 0; cot < 4; ++cot)
                    acc[rw][pt][cot] = __builtin_amdgcn_mfma_f32_16x16x32_bf16(areg[cot], bv, acc[rw][pt][cot], 0, 0, 0);
            }
        }
    }

    // ---- epilogue: per-half state bounce, tables separate from staging ----
    short* tbase = smem + 19584;     // [rw][y|c][64 px][72 ch-half]
    const int h0 = r0 - 1;
#pragma unroll
    for (int hh = 0; hh < 2; ++hh) {
        if (mode != 0) {
#pragma unroll
            for (int rw = 0; rw < 2; ++rw) {
                short* tb_y = tbase + rw * 9216;
                short* tb_c = tb_y + 4608;
#pragma unroll
                for (int k = 0; k < 2; ++k) if (pok[k]) {
                    int o = pvv[k] * 72 + 8 * (pg[k] ^ (pvv[k] & 3));
                    *(short8*)(tb_y + o) = yold8[rw][k];
                    if (mode == 1) *(short8*)(tb_c + o) = cold8[rw][k];
                }
            }
        }
        __syncthreads();
        // issue half-1 loads early; latency hides under half-0 processing
        if (hh == 0 && mode != 0) {
#pragma unroll
            for (int k = 0; k < 2; ++k) if (pok[k]) {
                int s = pvv[k] + 2;
                int xo = 8 * ((pg[k] + 8) ^ (s & 7));
#pragma unroll
                for (int rw = 0; rw < 2; ++rw) {
                    size_t off = prow[rw] + (size_t)s * 128 + xo;
                    yold8[rw][k] = *(const short8*)(Yp + off);
                    if (mode == 1) cold8[rw][k] = *(const short8*)(Cp + off);
                }
            }
        }
        if (cog == hh) {
#pragma unroll
            for (int rw = 0; rw < 2; ++rw) {
                short* tb_y = tbase + rw * 9216;
                short* tb_c = tb_y + 4608;
#pragma unroll
                for (int pt = 0; pt < 2; ++pt) {
                    const int px = pxg * 32 + pt * 16 + l15;
#pragma unroll
                    for (int cot = 0; cot < 4; ++cot) {
#pragma unroll
                        for (int reg = 0; reg < 4; ++reg) {
                            const int lch = cot * 16 + quad * 4 + reg;   // 0..63
                            const int slot = px * 72 + (lch ^ ((px & 3) << 3));
                            const float a = acc[rw][pt][cot][reg];
                            if (mode == 0) {
                                float c = fmaxf(MU_ * a - THR_, 0.f);
                                short cb16 = f2bf(c);
                                tb_y[slot] = cb16;
                                tb_c[slot] = cb16;
                            } else if (mode == 1) {
                                float yold = bf2f((unsigned short)tb_y[slot]);
                                float cold = bf2f((unsigned short)tb_c[slot]);
                                float c = fmaxf(yold + MU_ * a - THR_, 0.f);
                                tb_y[slot] = f2bf(c + beta * (c - cold));
                                tb_c[slot] = f2bf(c);
                            } else {
                                if (px < 56) {
                                    float yold = bf2f((unsigned short)tb_y[slot]);
                                    float c = fmaxf(yold + MU_ * a - THR_, 0.f);
                                    outp[((size_t)(n * 128 + hh * 64 + lch)) * 3136 + (h0 + rw) * 56 + px] = c;
                                }
                            }
                        }
                    }
                }
            }
        }
        if (mode != 2) {
            __syncthreads();
            for (int item = tid; item < 448; item += 256) {
                int vv = item >> 3, g = item & 7;
                int so = vv * 72 + 8 * (g ^ (vv & 3));
                int s = vv + 2;
                int xo = 8 * ((g + 8 * hh) ^ (s & 7));
#pragma unroll
                for (int rw = 0; rw < 2; ++rw) {
                    short* tb_y = tbase + rw * 9216;
                    short8 yv = *(const short8*)(tb_y + so);
                    short8 cv = *(const short8*)(tb_y + 4608 + so);
                    size_t off = prow[rw] + (size_t)s * 128 + xo;
                    *(short8*)(Yp + off) = yv;
                    *(short8*)(Cp + off) = cv;
                }
            }
        }
        if (hh == 0) __syncthreads();   // tables free before half-1 reuse
    }
}

// ---------------------------------------------------------------------------
// Transpose conv 128->64, row-PAIR blocks: rows r0,r0+1 from a shared 4-row
// Y window, 2 LDS passes over K chunk halves; pass-1 register-prefetched
// (T14). Wave = 64 ci x 16 px; acc[2 rows][4 cit]. Fused r = x - D^T y.
// grid = 448, same sid0 map as conv_fwd.
// LDS: 4x68x72 staging + 2 tables = 57.6 KB, 2 blocks/CU.
// ---------------------------------------------------------------------------
__global__ __launch_bounds__(256, 2) void conv_t(
    const short* __restrict__ Ypb,   // [n][58][68][128] bf16 swz
    const short* __restrict__ Wt2,   // [9][16][64][8] bf16 k-major chunks
    const short* __restrict__ Xp,    // [n][58][68][64] bf16 swz
    short* __restrict__ Rp) {        // [n][58][68][64] bf16 swz
    __shared__ __align__(16) short smem[28800];
    const int bid = blockIdx.x, tid = threadIdx.x;
    const int sid0 = (bid & 7) * 112 + (bid >> 3) * 2;
    const int n = sid0 / 56, r0 = sid0 - n * 56 + 1;
    const int lane = tid & 63, ct = tid >> 6, quad = lane >> 4, l15 = lane & 15;
    const short8* src = (const short8*)(Ypb + ((size_t)(n * 58 + (r0 - 1)) * 68) * 128);
    size_t prowX[2];
    prowX[0] = ((size_t)(n * 58 + r0) * 68) * 64;
    prowX[1] = prowX[0] + 68 * 64;

    // pre-loop coalesced prefetch of x rows (448 short8 items per row)
    short8 xold8[2][2];
    int pvv[2], pg[2]; bool pok[2];
#pragma unroll
    for (int k = 0; k < 2; ++k) {
        int item = tid + k * 256;
        pok[k] = item < 448;
        pvv[k] = item >> 3; pg[k] = item & 7;
        if (pok[k]) {
            int s = pvv[k] + 2;
            int xo = 8 * (pg[k] ^ (s & 7));
#pragma unroll
            for (int rw = 0; rw < 2; ++rw)
                xold8[rw][k] = *(const short8*)(Xp + prowX[rw] + (size_t)s * 64 + xo);
        }
    }

    zero_lds_pads4(smem, tid);
    // stage pass-0 (chunk half 0) of 4 rows, interior slots (1792 items)
    for (int j = tid; j < 1792; j += 256) {
        int sr = j >> 3, w = j & 7;
        int row = sr / 56, s = sr - row * 56 + 2;
        *(short8*)(smem + (row * 68 + s) * 72 + w * 8) = src[(row * 68 + s) * 16 + w];
    }

    f32x4 acc[2][4];                  // [rw][cit] : 64 ci x 16 px per wave
#pragma unroll
    for (int rw = 0; rw < 2; ++rw)
#pragma unroll
        for (int cit = 0; cit < 4; ++cit) acc[rw][cit] = (f32x4){0.f, 0.f, 0.f, 0.f};

    __syncthreads();

    // T14: issue pass-1 staging loads now; latency hides under pass-0 compute
    short8 pf[7];
#pragma unroll
    for (int k = 0; k < 7; ++k) {
        int j = tid + k * 256;
        if (j < 1792) {
            int sr = j >> 3, w = j & 7;
            int row = sr / 56, s = sr - row * 56 + 2;
            pf[k] = src[(row * 68 + s) * 16 + 8 + w];
        }
    }

#pragma unroll
    for (int p = 0; p < 2; ++p) {
        if (p) {
            __syncthreads();          // pass-0 B reads complete
#pragma unroll
            for (int k = 0; k < 7; ++k) {
                int j = tid + k * 256;
                if (j < 1792) {
                    int sr = j >> 3, w = j & 7;
                    int row = sr / 56, s = sr - row * 56 + 2;
                    *(short8*)(smem + (row * 68 + s) * 72 + w * 8) = pf[k];
                }
            }
            __syncthreads();
        }
#pragma unroll
        for (int f = 0; f < 18; ++f) {         // 18 k-frags; A shared by rows
            const int t = f >> 1, sh = f & 1;
            const int dh = t / 3, dw = t % 3;
            const int u = l15 + dw + 1;
            const int phys = (sh * 4 + quad) ^ (u & 7);
            short8 areg[4];
#pragma unroll
            for (int cit = 0; cit < 4; ++cit) {
                const int ci = cit * 16 + l15;
                areg[cit] = *(const short8*)(Wt2 +
                    ((size_t)((t * 16 + (p * 2 + sh) * 4 + quad) * 64 + ci)) * 8);
            }
#pragma unroll
            for (int rw = 0; rw < 2; ++rw) {
                const short8 bv = *(const short8*)(smem +
                    ((dh + rw) * 68 + ct * 16 + u) * 72 + phys * 8);
#pragma unroll
                for (int cit = 0; cit < 4; ++cit)
                    acc[rw][cit] = __builtin_amdgcn_mfma_f32_16x16x32_bf16(areg[cit], bv, acc[rw][cit], 0, 0, 0);
            }
        }
    }

    // ---- epilogue: r = x - acc via LDS bounce (tables beyond staging) ----
    short* tbase = smem + 19584;     // [rw][64 px][72 ch]
#pragma unroll
    for (int rw = 0; rw < 2; ++rw) {
#pragma unroll
        for (int k = 0; k < 2; ++k) if (pok[k]) {
            *(short8*)(tbase + rw * 4608 + pvv[k] * 72 + 8 * (pg[k] ^ (pvv[k] & 3))) = xold8[rw][k];
        }
    }
    __syncthreads();
    {
        const int px = ct * 16 + l15;
#pragma unroll
        for (int rw = 0; rw < 2; ++rw) {
            short* tb = tbase + rw * 4608;
#pragma unroll
            for (int cit = 0; cit < 4; ++cit) {
#pragma unroll
                for (int reg = 0; reg < 4; ++reg) {
                    const int cir = cit * 16 + quad * 4 + reg;
                    const int slot = px * 72 + (cir ^ ((px & 3) << 3));
                    float xo = bf2f((unsigned short)tb[slot]);
                    tb[slot] = f2bf(xo - acc[rw][cit][reg]);
                }
            }
        }
    }
    __syncthreads();
    for (int item = tid; item < 448; item += 256) {
        int vv = item >> 3, g = item & 7;
        int so = vv * 72 + 8 * (g ^ (vv & 3));
        int s = vv + 2;
        int xo = 8 * (g ^ (s & 7));
#pragma unroll
        for (int rw = 0; rw < 2; ++rw) {
            short8 val = *(const short8*)(tbase + rw * 4608 + so);
            *(short8*)(Rp + prowX[rw] + (size_t)s * 64 + xo) = val;
        }
    }
}

// ---------------------------------------------------------------------------
extern "C" void kernel_launch(void* const* d_in, const int* in_sizes, int n_in,
                              void* d_out, int out_size, void* d_ws, size_t ws_size,
                              hipStream_t stream) {
    const float* x = (const float*)d_in[0];   // [16,64,56,56] fp32
    const float* W = (const float*)d_in[1];   // [128,64,3,3]  fp32
    float* out = (float*)d_out;               // [16,128,56,56] fp32

    // ws layout (all bf16): Xp | Rp | Yp | Cp | Wf2 | Wt2  (~49 MB)
    const size_t XPN = (size_t)16 * 58 * 68 * 64;   // 4,038,656
    const size_t YPN = 2 * XPN;                      // 8,077,312
    short* Xp = (short*)d_ws;
    short* Rp = Xp + XPN;
    short* Yp = Rp + XPN;
    short* Cp = Yp + YPN;
    short* Wf2 = Cp + YPN;                // 73728 shorts
    short* Wt2 = Wf2 + 73728;             // 73728 shorts

    const int prep_blocks = ZB_ + 32 + 58 * 16;     // 1164
    hipLaunchKernelGGL(prep_kernel, dim3(prep_blocks), dim3(256), 0, stream,
                       x, W, Rp, Yp, Xp, Wf2, Wt2);

    dim3 b(256, 1, 1);
    // it0: c = shrink(MU * conv(x)); y = cp = c
    hipLaunchKernelGGL(conv_fwd, dim3(448), b, 0, stream, Xp, Wf2, Yp, Cp,
                       (float*)nullptr, 0, 0.f);
    double t = 1.0;
    for (int it = 1; it <= 5; ++it) {
        hipLaunchKernelGGL(conv_t, dim3(448), b, 0, stream, Yp, Wt2, Xp, Rp);
        double tn = (1.0 + sqrt(1.0 + 4.0 * t * t)) / 2.0;
        float beta = (float)((t - 1.0) / tn);
        hipLaunchKernelGGL(conv_fwd, dim3(448), b, 0, stream, Rp, Wf2, Yp, Cp,
                           (it == 5) ? out : (float*)nullptr, (it == 5) ? 2 : 1,
                           beta);
        t = tn;
    }
}